// Round 16
// baseline (131.418 us; speedup 1.0000x reference)
//
#include <hip/hip_runtime.h>
#include <hip/hip_bf16.h>
#include <stdint.h>

#define B_   8
#define L_   2048
#define D_   256
#define H_   256
#define TJ   32          // j-tile
#define NT   (L_/TJ)     // 64 tiles
#define BM   64          // rows per flash block
#define LOG2E 1.4426950408889634f

typedef short bf16x8 __attribute__((ext_vector_type(8)));
typedef short bf16x4 __attribute__((ext_vector_type(4)));
typedef float f32x4  __attribute__((ext_vector_type(4)));

#define MFMA(a,b,c) __builtin_amdgcn_mfma_f32_16x16x32_bf16(a,b,c,0,0,0)
#define EX2(x) __builtin_amdgcn_exp2f(x)

typedef unsigned int u32;
__device__ __forceinline__ void gload_lds16(const void* g, void* l){
  __builtin_amdgcn_global_load_lds((const __attribute__((address_space(1))) u32*)g,
                                   (__attribute__((address_space(3))) u32*)l, 16, 0, 0);
}

__device__ __forceinline__ unsigned short f2bf(float f){
  __hip_bfloat16 h = __float2bfloat16(f);
  unsigned short us;
  __builtin_memcpy(&us, &h, 2);
  return us;
}

// full barrier: staging landed + LDS writes visible + buffers reusable
__device__ __forceinline__ void bar_all(){
  asm volatile("s_waitcnt vmcnt(0) lgkmcnt(0)" ::: "memory");
  __builtin_amdgcn_s_barrier();
  __builtin_amdgcn_sched_barrier(0);
}

// ---------------- weight norm (both sets in one launch; y selects a/b)
// Also zero-inits the maxn slots (stream-ordered before hgemm's atomics).
__global__ __launch_bounds__(256) void wnorm_kernel(const float* __restrict__ av,
      const float* __restrict__ ag, const float* __restrict__ bv,
      const float* __restrict__ bg, unsigned short* __restrict__ wa,
      unsigned short* __restrict__ wb, float* __restrict__ maxn){
  int sel = blockIdx.y;
  if (blockIdx.x == 0 && threadIdx.x < 8) maxn[sel*8 + threadIdx.x] = 0.f;
  const float* v = sel ? bv : av;
  const float* g = sel ? bg : ag;
  unsigned short* w = sel ? wb : wa;
  int h = blockIdx.x;
  int d = threadIdx.x;
  float x = v[h*D_ + d];
  float sq = x*x;
  for (int off = 32; off; off >>= 1) sq += __shfl_down(sq, off, 64);
  __shared__ float red[4];
  int lane = threadIdx.x & 63, wid = threadIdx.x >> 6;
  if (lane == 0) red[wid] = sq;
  __syncthreads();
  float tot = red[0] + red[1] + red[2] + red[3];
  float scale = g[h] / sqrtf(tot);
  w[h*D_ + d] = f2bf(x * scale);
}

// ---------------- hx = bf16(scale * relu(x @ w^T + bias)), 64 rows x 256 cols.
// (R15 version, unchanged: coalesced LDS-staged loads, R=2 w blocking,
// coalesced h stores via xlk, row norms + one atomicMax per block.)
__global__ __launch_bounds__(256) void hgemm_kernel(const float* __restrict__ a,
      const float* __restrict__ b, const unsigned short* __restrict__ wa,
      const unsigned short* __restrict__ wb, const float* __restrict__ a_bias,
      const float* __restrict__ b_bias, const float* __restrict__ tau_ptr,
      unsigned short* __restrict__ ha, unsigned short* __restrict__ hb,
      unsigned short* __restrict__ aT, unsigned short* __restrict__ bT,
      float* __restrict__ rn_a, float* __restrict__ rn_b,
      float* __restrict__ maxn){
  __shared__ __align__(16) unsigned short xlk[64][256];
  __shared__ float redp[2][2][32];
  __shared__ float redm[4];
  int sel = blockIdx.y;
  const float* x = sel ? b : a;
  const unsigned short* w = sel ? wb : wa;
  const float* bias = sel ? b_bias : a_bias;
  unsigned short* hx = sel ? hb : ha;
  unsigned short* xT = sel ? bT : aT;
  float* rn = sel ? rn_b : rn_a;
  float scale = sel ? 1.0f : tau_ptr[0] * LOG2E;
  int m0 = blockIdx.x * 64;
  int bz = m0 / L_, l0 = m0 % L_;
  int tid = threadIdx.x;
  int lane = tid & 63, wid = tid >> 6;
  int rp = wid >> 1, ch = wid & 1;
  int p = lane & 15, q = lane >> 4;

  {
    int r0 = tid >> 6;
    int c  = (tid & 63) * 4;
    int slot = c >> 3, half = (c >> 2) & 1;
    #pragma unroll
    for (int it = 0; it < 16; ++it){
      int row = it*4 + r0;
      f32x4 v = *(const f32x4*)(x + (size_t)(m0 + row) * 256 + c);
      uint2 wv;
      wv.x = (u32)f2bf(v[0]) | ((u32)f2bf(v[1]) << 16);
      wv.y = (u32)f2bf(v[2]) | ((u32)f2bf(v[3]) << 16);
      *(uint2*)((char*)&xlk[row][0] + ((slot ^ (row & 7)) << 4) + half*8) = wv;
    }
  }
  __syncthreads();

  bf16x8 af[2][8];
  #pragma unroll
  for (int g = 0; g < 2; ++g){
    int row = rp*32 + g*16 + p;
    #pragma unroll
    for (int kk = 0; kk < 8; ++kk)
      af[g][kk] = *(const bf16x8*)((char*)&xlk[row][0] + (((kk*4 + q) ^ (row & 7)) << 4));
  }
  f32x4 acc[2][8];
  #pragma unroll
  for (int g = 0; g < 2; ++g)
    #pragma unroll
    for (int n = 0; n < 8; ++n) acc[g][n] = (f32x4){0.f,0.f,0.f,0.f};
  #pragma unroll
  for (int kk = 0; kk < 8; kk++){
    #pragma unroll
    for (int n = 0; n < 8; n++){
      bf16x8 bfr = *(const bf16x8*)(w + (size_t)(ch*128 + n*16 + p) * 256 + kk*32 + q*8);
      acc[0][n] = MFMA(af[0][kk], bfr, acc[0][n]);
      acc[1][n] = MFMA(af[1][kk], bfr, acc[1][n]);
    }
  }

  #pragma unroll
  for (int it = 0; it < 16; it++){
    int d = it*16 + (tid >> 4);
    int c = (tid & 15) * 4;
    bf16x4 v;
    #pragma unroll
    for (int j = 0; j < 4; j++){
      int row = c + j;
      v[j] = (short)*((const unsigned short*)((char*)&xlk[row][0]
                + (((d >> 3) ^ (row & 7)) << 4)) + (d & 7));
    }
    *(bf16x4*)(xT + ((size_t)bz*D_ + d)*L_ + l0 + c) = v;
  }
  __syncthreads();

  unsigned short* hl = &xlk[0][0];
  float rs[2][4] = {{0.f,0.f,0.f,0.f},{0.f,0.f,0.f,0.f}};
  #pragma unroll
  for (int g = 0; g < 2; ++g)
    #pragma unroll
    for (int n = 0; n < 8; ++n){
      float bv = bias[ch*128 + n*16 + p];
      #pragma unroll
      for (int r = 0; r < 4; ++r){
        int row = rp*32 + g*16 + q*4 + r;
        float vv = acc[g][n][r] + bv;
        vv = vv > 0.f ? vv : 0.f;
        float sv = vv * scale;
        rs[g][r] += sv * sv;
        hl[row*256 + ch*128 + n*16 + p] = f2bf(sv);
      }
    }
  #pragma unroll
  for (int off = 1; off < 16; off <<= 1)
    #pragma unroll
    for (int g = 0; g < 2; ++g)
      #pragma unroll
      for (int r = 0; r < 4; r++)
        rs[g][r] += __shfl_xor(rs[g][r], off, 64);
  if (p == 0){
    #pragma unroll
    for (int g = 0; g < 2; ++g)
      #pragma unroll
      for (int r = 0; r < 4; ++r)
        redp[ch][rp][g*16 + q*4 + r] = rs[g][r];
  }
  __syncthreads();

  float lmax = 0.f;
  #pragma unroll
  for (int g = 0; g < 2; ++g)
    #pragma unroll
    for (int r = 0; r < 4; ++r){
      int idx = g*16 + q*4 + r;
      float tot = redp[0][rp][idx] + redp[1][rp][idx];
      float rv = sqrtf(tot) * 1.01f;
      lmax = fmaxf(lmax, rv);
      if (ch == 0 && p == 0) rn[m0 + rp*32 + idx] = rv;
    }
  lmax = fmaxf(lmax, __shfl_xor(lmax, 16, 64));
  lmax = fmaxf(lmax, __shfl_xor(lmax, 32, 64));
  if (lane == 0) redm[wid] = lmax;

  #pragma unroll
  for (int i = 0; i < 8; ++i){
    int idx = i*256 + tid;
    bf16x8 hv = *(const bf16x8*)(hl + idx*8);
    *(bf16x8*)(hx + (size_t)m0*256 + (size_t)idx*8) = hv;
  }
  __syncthreads();
  if (tid == 0){
    float bm = fmaxf(fmaxf(redm[0], redm[1]), fmaxf(redm[2], redm[3]));
    atomicMax((u32*)&maxn[sel*8 + bz], __float_as_uint(bm));
  }
}

// ---------------- fused flash alignment, SOFTWARE-PIPELINED:
// static row-max makes tiles independent -> per iteration run QK(t+1) and
// PV(t) concurrently (two MFMA streams), exp(t+1) overlaps PV tail.
// TJ=32, everything double-buffered (HBT/VP/WT), ONE bar_all per tile.
// 256 threads (4 waves = 2 wr x 2 wc), 64 rows, 2 blocks/CU (LDS ~75KB).
// Masks bit-packed via ballot. V repacked [128][64] (d-pairs) for 8-slot XOR.
__global__ __launch_bounds__(256, 2) void flash_kernel(
    const unsigned short* __restrict__ ha, const unsigned short* __restrict__ hb,
    const unsigned short* __restrict__ aT, const unsigned short* __restrict__ bT,
    const int* __restrict__ mask_a, const int* __restrict__ mask_b,
    const float* __restrict__ rn_a, const float* __restrict__ rn_b,
    const float* __restrict__ maxn, float* __restrict__ out)
{
  __shared__ __align__(16) unsigned short HBT[2][8192];  // [buf][32 j-rows][256]
  __shared__ __align__(16) unsigned short VP [2][8192];  // [buf][128 d-pairs][64]
  __shared__ __align__(16) unsigned short WT [2][2560];  // [buf][wr][32 rows][40]
  __shared__ u32 MSKW[64];                               // bit-packed masks
  __shared__ float SST[4][32];

  const int bid = blockIdx.x;
  const int s   = bid & 15;             // stream; XCD = bid%8 = bz
  const int dir = s >> 3;
  const int bz  = s & 7;
  const int i0  = (bid >> 4) * BM;
  const int tid = threadIdx.x;
  const int lane = tid & 63;
  const int wid  = tid >> 6;            // 0..3
  const int wr = wid >> 1, wc = wid & 1;
  const int p = lane & 15, q = lane >> 4;

  const unsigned short* hA = dir ? hb : ha;
  const unsigned short* hB = dir ? ha : hb;
  const unsigned short* vT = dir ? aT : bT;
  const int* mask = dir ? mask_a : mask_b;
  const float* rnA = dir ? rn_b : rn_a;
  const float mxB  = maxn[(dir ^ 1)*8 + bz];
  float* outp = out + ((size_t)dir * B_ + bz) * L_ * D_;

  const unsigned short* hAp = hA + (size_t)bz * L_ * H_;
  const unsigned short* hBp = hB + (size_t)bz * L_ * H_;
  const unsigned short* vTp = vT + (size_t)bz * D_ * L_;
  const int* mp = mask + bz * L_;

  // A fragments: this wave's 32 rows (two 16-row groups)
  bf16x8 af[2][8];
  #pragma unroll
  for (int g = 0; g < 2; ++g)
    #pragma unroll
    for (int kk = 0; kk < 8; ++kk)
      af[g][kk] = *(const bf16x8*)(hAp + (size_t)(i0 + wr*32 + g*16 + p) * H_ + kk*32 + q*8);

  // static per-row softmax bound
  float m_p[2];
  #pragma unroll
  for (int g = 0; g < 2; ++g)
    m_p[g] = rnA[bz*L_ + i0 + wr*32 + g*16 + p] * mxB;

  // bit-packed masks (ballot: 64 j per op, result uniform across wave)
  #pragma unroll
  for (int k = 0; k < 8; ++k){
    int idx = wid*8 + k;
    unsigned long long bb = __ballot(mp[idx*64 + lane] > 0);
    if (lane == 0){ MSKW[idx*2] = (u32)bb; MSKW[idx*2+1] = (u32)(bb >> 32); }
  }

  f32x4 acc[2][8];
  #pragma unroll
  for (int g = 0; g < 2; ++g)
    #pragma unroll
    for (int n = 0; n < 8; ++n) acc[g][n] = (f32x4){0.f,0.f,0.f,0.f};
  float s_run[2];
  s_run[0] = s_run[1] = 0.f;

  #define STAGE_HB(bb, jj0) do {                                                  \
    _Pragma("unroll")                                                             \
    for (int k = 0; k < 4; ++k){                                                  \
      int rr = k*8 + (tid >> 5);                                                  \
      int sp = (tid & 31) ^ (rr & 7);                                             \
      gload_lds16(hBp + (size_t)((jj0) + rr) * H_ + sp*8,                         \
                  &HBT[bb][0] + k*2048 + tid*8);                                  \
    }                                                                             \
  } while(0)
  // V element (d, jj) lives at row R=d>>1, logical slot l=(d&1)*4+(jj>>3),
  // physical slot l^(R&7); staging enumerates (R,ph) and inverts.
  #define STAGE_VP(bb, jj0) do {                                                  \
    _Pragma("unroll")                                                             \
    for (int k = 0; k < 4; ++k){                                                  \
      int c = k*256 + tid;                                                        \
      int R = c >> 3, ph = c & 7;                                                 \
      int l = ph ^ (R & 7);                                                       \
      int d = 2*R + (l >> 2);                                                     \
      int jj = (l & 3) * 8;                                                       \
      gload_lds16(vTp + (size_t)d * L_ + (jj0) + jj,                              \
                  &VP[bb][0] + c*8);                                              \
    }                                                                             \
  } while(0)

  #define QK_TILE(buf, accp) do {                                                 \
    _Pragma("unroll")                                                             \
    for (int kk = 0; kk < 8; ++kk){                                               \
      const int rb = wc*16 + p;                                                   \
      const int sp = ((kk*4 + q) ^ (p & 7)) * 8;                                  \
      bf16x8 b0 = *(const bf16x8*)(&HBT[buf][0] + rb*256 + sp);                   \
      accp[0] = MFMA(b0, af[0][0+kk], accp[0]);                                   \
      accp[1] = MFMA(b0, af[1][0+kk], accp[1]);                                   \
    }                                                                             \
  } while(0)

  #define EXP_WT(tt, wb, accp) do {                                               \
    u32 mw = MSKW[tt];                                                            \
    _Pragma("unroll")                                                             \
    for (int g = 0; g < 2; ++g){                                                  \
      float ww[4];                                                                \
      _Pragma("unroll")                                                           \
      for (int r = 0; r < 4; ++r){                                                \
        float mm = ((mw >> (wc*16 + q*4 + r)) & 1u) ? 0.f : -1e9f;                \
        ww[r] = EX2(accp[g][r] + mm - m_p[g]);                                    \
      }                                                                           \
      s_run[g] += (ww[0] + ww[1]) + (ww[2] + ww[3]);                              \
      uint2 wv;                                                                   \
      wv.x = (u32)f2bf(ww[0]) | ((u32)f2bf(ww[1]) << 16);                         \
      wv.y = (u32)f2bf(ww[2]) | ((u32)f2bf(ww[3]) << 16);                         \
      int row = g*16 + p;                                                         \
      *(uint2*)((char*)&WT[wb][0] + (wr*1280 + row*40 + wc*16 + q*4)*2) = wv;     \
    }                                                                             \
  } while(0)

  // prologue: stage t0 (both), t1 (HB only); QK(0)+exp(0)
  STAGE_HB(0, 0);
  STAGE_VP(0, 0);
  STAGE_HB(1, TJ);
  bar_all();
  {
    f32x4 accp[2] = {(f32x4){0.f,0.f,0.f,0.f}, (f32x4){0.f,0.f,0.f,0.f}};
    __builtin_amdgcn_s_setprio(1);
    QK_TILE(0, accp);
    __builtin_amdgcn_s_setprio(0);
    EXP_WT(0, 0, accp);
  }

  for (int t = 0; t < NT; ++t){
    bar_all();   // WT(t) visible; HBT[(t+1)&1], VP[t&1] landed; buffers rotable
    const int cb = t & 1;

    bf16x8 wf[2];
    #pragma unroll
    for (int g = 0; g < 2; ++g){
      int row = g*16 + p;
      wf[g] = *(const bf16x8*)((char*)&WT[cb][0] + (wr*1280 + row*40 + q*8)*2);
    }

    if (t + 2 < NT) STAGE_HB(cb, (t+2)*TJ);       // buf (t+2)&1 == cb
    if (t + 1 < NT) STAGE_VP(cb ^ 1, (t+1)*TJ);

    f32x4 accp[2] = {(f32x4){0.f,0.f,0.f,0.f}, (f32x4){0.f,0.f,0.f,0.f}};
    __builtin_amdgcn_s_setprio(1);
    if (t + 1 < NT) QK_TILE(cb ^ 1, accp);        // QK(t+1) || PV(t)
    #pragma unroll
    for (int n = 0; n < 8; ++n){
      const int d = wc*128 + n*16 + p;
      const int R = d >> 1;
      const int ph = ((d & 1)*4 + q) ^ (R & 7);
      bf16x8 vf = *(const bf16x8*)(&VP[cb][0] + R*64 + ph*8);
      acc[0][n] = MFMA(wf[0], vf, acc[0][n]);
      acc[1][n] = MFMA(wf[1], vf, acc[1][n]);
    }
    __builtin_amdgcn_s_setprio(0);
    if (t + 1 < NT) EXP_WT(t+1, cb ^ 1, accp);
  }
  #undef STAGE_HB
  #undef STAGE_VP
  #undef QK_TILE
  #undef EXP_WT

  // ---- finish: q-reduce s (row p layout), wc-pair merge via SST, store
  s_run[0] += __shfl_xor(s_run[0], 16, 64);
  s_run[0] += __shfl_xor(s_run[0], 32, 64);
  s_run[1] += __shfl_xor(s_run[1], 16, 64);
  s_run[1] += __shfl_xor(s_run[1], 32, 64);
  if (q == 0){
    SST[wid][p]      = s_run[0];
    SST[wid][16 + p] = s_run[1];
  }
  __syncthreads();
  float invS[2][4];
  #pragma unroll
  for (int g = 0; g < 2; ++g)
    #pragma unroll
    for (int r = 0; r < 4; ++r){
      int idx = g*16 + q*4 + r;
      invS[g][r] = 1.0f / (SST[wr*2][idx] + SST[wr*2 + 1][idx]);
    }

  #pragma unroll
  for (int g = 0; g < 2; ++g)
    #pragma unroll
    for (int n = 0; n < 8; ++n)
      #pragma unroll
      for (int r = 0; r < 4; ++r){
        int row = i0 + wr*32 + g*16 + q*4 + r;
        outp[(size_t)row * D_ + wc*128 + n*16 + p] = acc[g][n][r] * invS[g][r];
      }
}

extern "C" void kernel_launch(void* const* d_in, const int* in_sizes, int n_in,
                              void* d_out, int out_size, void* d_ws, size_t ws_size,
                              hipStream_t stream) {
  const float* a      = (const float*)d_in[0];
  const float* b      = (const float*)d_in[1];
  const int*   mask_a = (const int*)d_in[2];
  const int*   mask_b = (const int*)d_in[3];
  const float* a_v    = (const float*)d_in[4];
  const float* a_g    = (const float*)d_in[5];
  const float* a_bias = (const float*)d_in[6];
  const float* b_v    = (const float*)d_in[7];
  const float* b_g    = (const float*)d_in[8];
  const float* b_bias = (const float*)d_in[9];
  const float* tau    = (const float*)d_in[10];

  float* out = (float*)d_out;

  char* ws = (char*)d_ws;
  const size_t SZ_W  = (size_t)H_ * D_ * 2;        // 128 KB
  const size_t SZ_H  = (size_t)B_ * L_ * H_ * 2;   // 8 MB
  unsigned short* wa = (unsigned short*)(ws);
  unsigned short* wb = (unsigned short*)(ws + SZ_W);
  unsigned short* ha = (unsigned short*)(ws + 2*SZ_W);
  unsigned short* hb = (unsigned short*)(ws + 2*SZ_W + SZ_H);
  unsigned short* aT = (unsigned short*)(ws + 2*SZ_W + 2*SZ_H);
  unsigned short* bT = (unsigned short*)(ws + 2*SZ_W + 3*SZ_H);
  float* rn_a = (float*)(ws + 2*SZ_W + 4*SZ_H);
  float* rn_b = rn_a + (size_t)B_ * L_;
  float* maxn = rn_b + (size_t)B_ * L_;            // 16 floats
  size_t need = 2*SZ_W + 4*SZ_H + 2*(size_t)B_*L_*4 + 64;
  if (ws_size < need) return;

  // 1. normalized weights (both, one launch) + maxn init
  wnorm_kernel<<<dim3(H_, 2), 256, 0, stream>>>(a_v, a_g, b_v, b_g, wa, wb, maxn);

  // 2. h = bf16(scale*relu(x@w^T+bias)) + transposed copies + row norms
  {
    dim3 g((B_*L_)/64, 2);
    hgemm_kernel<<<g, 256, 0, stream>>>(a, b, wa, wb, a_bias, b_bias, tau,
                                        ha, hb, aT, bT, rn_a, rn_b, maxn);
  }

  // 3. fused flash alignment, both directions (512 blocks = 2/CU, XCD-affine)
  {
    flash_kernel<<<dim3((L_/BM) * B_ * 2), 256, 0, stream>>>(
        ha, hb, aT, bT, mask_a, mask_b, rn_a, rn_b, maxn, out);
  }
}

// Round 17
// 121.664 us; speedup vs baseline: 1.0802x; 1.0802x over previous
//
#include <hip/hip_runtime.h>
#include <hip/hip_bf16.h>
#include <stdint.h>

#define B_   8
#define L_   2048
#define D_   256
#define H_   256
#define TJ   64          // j-tile
#define NT   (L_/TJ)     // 32 tiles
#define BM   64          // rows per flash block
#define LOG2E 1.4426950408889634f

typedef short bf16x8 __attribute__((ext_vector_type(8)));
typedef short bf16x4 __attribute__((ext_vector_type(4)));
typedef unsigned short u16x4 __attribute__((ext_vector_type(4)));
typedef float f32x4  __attribute__((ext_vector_type(4)));

#define MFMA(a,b,c) __builtin_amdgcn_mfma_f32_16x16x32_bf16(a,b,c,0,0,0)
#define EX2(x) __builtin_amdgcn_exp2f(x)

typedef unsigned int u32;
__device__ __forceinline__ void gload_lds16(const void* g, void* l){
  __builtin_amdgcn_global_load_lds((const __attribute__((address_space(1))) u32*)g,
                                   (__attribute__((address_space(3))) u32*)l, 16, 0, 0);
}

__device__ __forceinline__ unsigned short f2bf(float f){
  __hip_bfloat16 h = __float2bfloat16(f);
  unsigned short us;
  __builtin_memcpy(&us, &h, 2);
  return us;
}
__device__ __forceinline__ float bf2f(unsigned short u){
  u32 t = ((u32)u) << 16;
  float f;
  __builtin_memcpy(&f, &t, 4);
  return f;
}

// LDS-visibility barrier (does NOT drain vmcnt -> prefetch survives)
__device__ __forceinline__ void bar_lgkm(){
  asm volatile("s_waitcnt lgkmcnt(0)" ::: "memory");
  __builtin_amdgcn_s_barrier();
  __builtin_amdgcn_sched_barrier(0);
}
// full barrier: staging landed + everyone done with current buffers
__device__ __forceinline__ void bar_all(){
  asm volatile("s_waitcnt vmcnt(0) lgkmcnt(0)" ::: "memory");
  __builtin_amdgcn_s_barrier();
  __builtin_amdgcn_sched_barrier(0);
}

// ---------------- weight norm (both sets in one launch; y selects a/b)
// Also zero-inits the maxn slots (stream-ordered before hgemm's atomics).
__global__ __launch_bounds__(256) void wnorm_kernel(const float* __restrict__ av,
      const float* __restrict__ ag, const float* __restrict__ bv,
      const float* __restrict__ bg, unsigned short* __restrict__ wa,
      unsigned short* __restrict__ wb, float* __restrict__ maxn){
  int sel = blockIdx.y;
  if (blockIdx.x == 0 && threadIdx.x < 8) maxn[sel*8 + threadIdx.x] = 0.f;
  const float* v = sel ? bv : av;
  const float* g = sel ? bg : ag;
  unsigned short* w = sel ? wb : wa;
  int h = blockIdx.x;
  int d = threadIdx.x;
  float x = v[h*D_ + d];
  float sq = x*x;
  for (int off = 32; off; off >>= 1) sq += __shfl_down(sq, off, 64);
  __shared__ float red[4];
  int lane = threadIdx.x & 63, wid = threadIdx.x >> 6;
  if (lane == 0) red[wid] = sq;
  __syncthreads();
  float tot = red[0] + red[1] + red[2] + red[3];
  float scale = g[h] / sqrtf(tot);
  w[h*D_ + d] = f2bf(x * scale);
}

// ---------------- hx = bf16(scale * relu(x @ w^T + bias)), 64 rows x 256 cols.
// Waves: 2 rowpairs (rp: 32 rows, af[2][8]) x 2 colhalves (ch: 128 cols) ->
// each w load feeds 2 MFMAs and per-wave w traffic halves (64 KB vs 128 KB).
// h stores packed through the (dead-after-af) xlk buffer -> coalesced b128.
// Row norms merged across the ch pair via LDS; one atomicMax per block.
__global__ __launch_bounds__(256) void hgemm_kernel(const float* __restrict__ a,
      const float* __restrict__ b, const unsigned short* __restrict__ wa,
      const unsigned short* __restrict__ wb, const float* __restrict__ a_bias,
      const float* __restrict__ b_bias, const float* __restrict__ tau_ptr,
      unsigned short* __restrict__ ha, unsigned short* __restrict__ hb,
      unsigned short* __restrict__ aT, unsigned short* __restrict__ bT,
      float* __restrict__ rn_a, float* __restrict__ rn_b,
      float* __restrict__ maxn){
  __shared__ __align__(16) unsigned short xlk[64][256];   // 32 KB, swizzled; reused as h buffer
  __shared__ float redp[2][2][32];                        // [ch][rp][row-in-32]
  __shared__ float redm[4];
  int sel = blockIdx.y;
  const float* x = sel ? b : a;
  const unsigned short* w = sel ? wb : wa;
  const float* bias = sel ? b_bias : a_bias;
  unsigned short* hx = sel ? hb : ha;
  unsigned short* xT = sel ? bT : aT;
  float* rn = sel ? rn_b : rn_a;
  float scale = sel ? 1.0f : tau_ptr[0] * LOG2E;
  int m0 = blockIdx.x * 64;
  int bz = m0 / L_, l0 = m0 % L_;
  int tid = threadIdx.x;
  int lane = tid & 63, wid = tid >> 6;
  int rp = wid >> 1, ch = wid & 1;
  int p = lane & 15, q = lane >> 4;

  // phase 1: coalesced load + convert + swizzled LDS store
  {
    int r0 = tid >> 6;            // row within 4-row group
    int c  = (tid & 63) * 4;      // bf16 col
    int slot = c >> 3, half = (c >> 2) & 1;
    #pragma unroll
    for (int it = 0; it < 16; ++it){
      int row = it*4 + r0;
      f32x4 v = *(const f32x4*)(x + (size_t)(m0 + row) * 256 + c);
      uint2 wv;
      wv.x = (u32)f2bf(v[0]) | ((u32)f2bf(v[1]) << 16);
      wv.y = (u32)f2bf(v[2]) | ((u32)f2bf(v[3]) << 16);
      *(uint2*)((char*)&xlk[row][0] + ((slot ^ (row & 7)) << 4) + half*8) = wv;
    }
  }
  __syncthreads();

  // phase 2: af[2][8] (32 rows) from LDS, R=2 MFMA over this wave's 128 w-cols
  bf16x8 af[2][8];
  #pragma unroll
  for (int g = 0; g < 2; ++g){
    int row = rp*32 + g*16 + p;
    #pragma unroll
    for (int kk = 0; kk < 8; ++kk)
      af[g][kk] = *(const bf16x8*)((char*)&xlk[row][0] + (((kk*4 + q) ^ (row & 7)) << 4));
  }
  f32x4 acc[2][8];
  #pragma unroll
  for (int g = 0; g < 2; ++g)
    #pragma unroll
    for (int n = 0; n < 8; ++n) acc[g][n] = (f32x4){0.f,0.f,0.f,0.f};
  #pragma unroll
  for (int kk = 0; kk < 8; kk++){
    #pragma unroll
    for (int n = 0; n < 8; n++){
      bf16x8 bfr = *(const bf16x8*)(w + (size_t)(ch*128 + n*16 + p) * 256 + kk*32 + q*8);
      acc[0][n] = MFMA(af[0][kk], bfr, acc[0][n]);
      acc[1][n] = MFMA(af[1][kk], bfr, acc[1][n]);
    }
  }

  // transpose-out from xlk (before xlk is overwritten with h)
  #pragma unroll
  for (int it = 0; it < 16; it++){
    int d = it*16 + (tid >> 4);
    int c = (tid & 15) * 4;
    bf16x4 v;
    #pragma unroll
    for (int j = 0; j < 4; j++){
      int row = c + j;
      v[j] = (short)*((const unsigned short*)((char*)&xlk[row][0]
                + (((d >> 3) ^ (row & 7)) << 4)) + (d & 7));
    }
    *(bf16x4*)(xT + ((size_t)bz*D_ + d)*L_ + l0 + c) = v;
  }
  __syncthreads();   // all xlk reads (af + transpose) done

  // epilogue: bias + relu + scale; h -> xlk (linear layout); partial row norms
  unsigned short* hl = &xlk[0][0];
  float rs[2][4] = {{0.f,0.f,0.f,0.f},{0.f,0.f,0.f,0.f}};
  #pragma unroll
  for (int g = 0; g < 2; ++g)
    #pragma unroll
    for (int n = 0; n < 8; ++n){
      float bv = bias[ch*128 + n*16 + p];
      #pragma unroll
      for (int r = 0; r < 4; ++r){
        int row = rp*32 + g*16 + q*4 + r;
        float vv = acc[g][n][r] + bv;
        vv = vv > 0.f ? vv : 0.f;
        float sv = vv * scale;
        rs[g][r] += sv * sv;
        hl[row*256 + ch*128 + n*16 + p] = f2bf(sv);
      }
    }
  #pragma unroll
  for (int off = 1; off < 16; off <<= 1)
    #pragma unroll
    for (int g = 0; g < 2; ++g)
      #pragma unroll
      for (int r = 0; r < 4; r++)
        rs[g][r] += __shfl_xor(rs[g][r], off, 64);
  if (p == 0){
    #pragma unroll
    for (int g = 0; g < 2; ++g)
      #pragma unroll
      for (int r = 0; r < 4; ++r)
        redp[ch][rp][g*16 + q*4 + r] = rs[g][r];
  }
  __syncthreads();   // h writes + partials visible

  // merge ch partials, row norms, block max
  float lmax = 0.f;
  #pragma unroll
  for (int g = 0; g < 2; ++g)
    #pragma unroll
    for (int r = 0; r < 4; ++r){
      int idx = g*16 + q*4 + r;
      float tot = redp[0][rp][idx] + redp[1][rp][idx];
      float rv = sqrtf(tot) * 1.01f;   // covers bf16 rounding + accum error
      lmax = fmaxf(lmax, rv);
      if (ch == 0 && p == 0) rn[m0 + rp*32 + idx] = rv;
    }
  lmax = fmaxf(lmax, __shfl_xor(lmax, 16, 64));
  lmax = fmaxf(lmax, __shfl_xor(lmax, 32, 64));
  if (lane == 0) redm[wid] = lmax;

  // coalesced h store-out (b128)
  #pragma unroll
  for (int i = 0; i < 8; ++i){
    int idx = i*256 + tid;
    bf16x8 hv = *(const bf16x8*)(hl + idx*8);
    *(bf16x8*)(hx + (size_t)m0*256 + (size_t)idx*8) = hv;
  }
  __syncthreads();
  if (tid == 0){
    float bm = fmaxf(fmaxf(redm[0], redm[1]), fmaxf(redm[2], redm[3]));
    atomicMax((u32*)&maxn[sel*8 + bz], __float_as_uint(bm));
  }
}

// ---------------- fused flash alignment: 256 threads (4 waves = 2 wr x 2 wc),
// 64 rows/block, TWO independent blocks per CU. Per-wave math: swapped-QK,
// static Cauchy-Schwarz row-max, packed WT, XOR swizzles. Single-buffered
// staging; HB prefetch for t+1 hidden under PV(t). (Measured 93 us; 7
// scheduling variants all null/negative -> converged, kept verbatim.)
__global__ __launch_bounds__(256, 2) void flash_kernel(
    const unsigned short* __restrict__ ha, const unsigned short* __restrict__ hb,
    const unsigned short* __restrict__ aT, const unsigned short* __restrict__ bT,
    const int* __restrict__ mask_a, const int* __restrict__ mask_b,
    const float* __restrict__ rn_a, const float* __restrict__ rn_b,
    const float* __restrict__ maxn, float* __restrict__ out)
{
  __shared__ __align__(16) unsigned short HBT[64][256];   // 32 KB
  __shared__ __align__(16) unsigned short VTL[256][64];   // 32 KB
  __shared__ __align__(16) unsigned short WT[2][32][64];  // 8 KB (16B slot ^= row&7)
  __shared__ unsigned short MSKB[2048];                   // 4 KB bf16 mask terms
  __shared__ float SST[4][32];

  const int bid = blockIdx.x;
  const int s   = bid & 15;             // stream; XCD = bid%8 = bz
  const int dir = s >> 3;
  const int bz  = s & 7;
  const int i0  = (bid >> 4) * BM;
  const int tid = threadIdx.x;
  const int lane = tid & 63;
  const int wid  = tid >> 6;            // 0..3
  const int wr = wid >> 1, wc = wid & 1;
  const int p = lane & 15, q = lane >> 4;

  const unsigned short* hA = dir ? hb : ha;
  const unsigned short* hB = dir ? ha : hb;
  const unsigned short* vT = dir ? aT : bT;
  const int* mask = dir ? mask_a : mask_b;
  const float* rnA = dir ? rn_b : rn_a;
  const float mxB  = maxn[(dir ^ 1)*8 + bz];
  float* outp = out + ((size_t)dir * B_ + bz) * L_ * D_;

  const unsigned short* hAp = hA + (size_t)bz * L_ * H_;
  const unsigned short* hBp = hB + (size_t)bz * L_ * H_;
  const unsigned short* vTp = vT + (size_t)bz * D_ * L_;
  const int* mp = mask + bz * L_;

  // staging geometry: 256 threads x 8 x 16B per 32KB buffer
  const int hb_r0 = tid >> 5;           // + k*8
  const int hb_s  = tid & 31;
  const int vt_r0 = tid >> 3;           // + k*32
  const int vt_s  = tid & 7;

  // A fragments: this wave's 32 rows (two 16-row groups)
  bf16x8 af[2][8];
  #pragma unroll
  for (int g = 0; g < 2; ++g)
    #pragma unroll
    for (int kk = 0; kk < 8; ++kk)
      af[g][kk] = *(const bf16x8*)(hAp + (size_t)(i0 + wr*32 + g*16 + p) * H_ + kk*32 + q*8);

  // static per-row softmax bound (rows i = i0+wr*32+g*16+p)
  float m_p[2];
  #pragma unroll
  for (int g = 0; g < 2; ++g)
    m_p[g] = rnA[bz*L_ + i0 + wr*32 + g*16 + p] * mxB;

  // masks -> LDS as bf16 (prologue)
  #pragma unroll
  for (int i = 0; i < 8; ++i){
    int idx = tid + i*256;
    MSKB[idx] = f2bf((mp[idx] > 0) ? 0.f : -1e9f);
  }

  f32x4 acc[2][8];
  #pragma unroll
  for (int g = 0; g < 2; ++g)
    #pragma unroll
    for (int n = 0; n < 8; ++n) acc[g][n] = (f32x4){0.f,0.f,0.f,0.f};
  float s_run[2];
  s_run[0] = s_run[1] = 0.f;

  #define STAGE_HB(jj0) do {                                                      \
    _Pragma("unroll")                                                             \
    for (int k = 0; k < 8; ++k){                                                  \
      int rr = k*8 + hb_r0;                                                       \
      int sp = hb_s ^ (rr & 7);                                                   \
      gload_lds16(hBp + (size_t)((jj0) + rr) * H_ + sp*8,                         \
                  &HBT[0][0] + k*2048 + tid*8);                                   \
    }                                                                             \
  } while(0)
  #define STAGE_VT(jj0) do {                                                      \
    _Pragma("unroll")                                                             \
    for (int k = 0; k < 8; ++k){                                                  \
      int rr = k*32 + vt_r0;                                                      \
      int sp = vt_s ^ (rr & 7);                                                   \
      gload_lds16(vTp + (size_t)rr * L_ + (jj0) + sp*8,                           \
                  &VTL[0][0] + k*2048 + tid*8);                                   \
    }                                                                             \
  } while(0)

  STAGE_HB(0);
  STAGE_VT(0);
  bar_all();   // prologue: buffers + masks ready

  for (int jt = 0; jt < NT; ++jt){
    const int j0 = jt * TJ;

    // ---- QK swapped: accp[g][cg] reg r = P[i = wr*32+g*16+p][j = j0+wc*32+cg*16+q*4+r]
    f32x4 accp[2][2];
    #pragma unroll
    for (int g = 0; g < 2; ++g)
      #pragma unroll
      for (int cg = 0; cg < 2; ++cg) accp[g][cg] = (f32x4){0.f,0.f,0.f,0.f};
    __builtin_amdgcn_s_setprio(1);
    #pragma unroll
    for (int kk = 0; kk < 8; ++kk){
      const int rb = wc*32 + p;
      const int sp = ((kk*4 + q) ^ (p & 7)) * 8;
      bf16x8 b0 = *(const bf16x8*)(&HBT[0][0] + rb*256 + sp);
      bf16x8 b1 = *(const bf16x8*)(&HBT[0][0] + (rb+16)*256 + sp);
      accp[0][0] = MFMA(b0, af[0][kk], accp[0][0]);
      accp[1][0] = MFMA(b0, af[1][kk], accp[1][0]);
      accp[0][1] = MFMA(b1, af[0][kk], accp[0][1]);
      accp[1][1] = MFMA(b1, af[1][kk], accp[1][1]);
    }
    __builtin_amdgcn_s_setprio(0);

    // ---- mask terms (bf16 broadcast b64 reads; reg r matches col q*4+r)
    u16x4 k0 = *(const u16x4*)(&MSKB[j0 + wc*32 + q*4]);
    u16x4 k1 = *(const u16x4*)(&MSKB[j0 + wc*32 + 16 + q*4]);
    f32x4 mm0, mm1;
    #pragma unroll
    for (int r = 0; r < 4; ++r){ mm0[r] = bf2f(k0[r]); mm1[r] = bf2f(k1[r]); }

    // ---- W = exp2(P + mask - m_static); in-lane s; packed b64 WT writes
    #pragma unroll
    for (int g = 0; g < 2; ++g){
      #pragma unroll
      for (int cg = 0; cg < 2; ++cg){
        const f32x4 mm = cg ? mm1 : mm0;
        float w0 = EX2(accp[g][cg][0] + mm[0] - m_p[g]);
        float w1 = EX2(accp[g][cg][1] + mm[1] - m_p[g]);
        float w2 = EX2(accp[g][cg][2] + mm[2] - m_p[g]);
        float w3 = EX2(accp[g][cg][3] + mm[3] - m_p[g]);
        s_run[g] += (w0 + w1) + (w2 + w3);
        uint2 wv;
        wv.x = (u32)f2bf(w0) | ((u32)f2bf(w1) << 16);
        wv.y = (u32)f2bf(w2) | ((u32)f2bf(w3) << 16);
        int row = g*16 + p;
        int sl  = (wc*4 + cg*2 + (q>>1)) ^ (row & 7);
        *(uint2*)(&WT[wr][0][0] + row*64 + (sl<<3) + ((q&1)<<2)) = wv;
      }
    }
    bar_lgkm();   // WT visible to wc partner; all QK reads of HBT done

    // prefetch next HB tile under PV (overwrites HBT; QK reads finished)
    if (jt + 1 < NT) STAGE_HB(j0 + TJ);

    bf16x8 wf[2][2];
    #pragma unroll
    for (int g = 0; g < 2; ++g)
      #pragma unroll
      for (int ks = 0; ks < 2; ++ks){
        int row = g*16 + p;
        wf[g][ks] = *(const bf16x8*)(&WT[wr][0][0] + row*64
                                     + ((((ks*4 + q) ^ (row & 7)))<<3));
      }

    // ---- PV: acc += W[32 rows][64 j] @ V[64 j][this wave's 128 d-cols]
    __builtin_amdgcn_s_setprio(1);
    #pragma unroll
    for (int n = 0; n < 8; ++n){
      const int d = wc*128 + n*16 + p;
      #pragma unroll
      for (int ks = 0; ks < 2; ++ks){
        const int sp = ((ks*4 + q) ^ (d & 7)) * 8;
        bf16x8 vf = *(const bf16x8*)(&VTL[0][0] + d*64 + sp);
        acc[0][n] = MFMA(wf[0][ks], vf, acc[0][n]);
        acc[1][n] = MFMA(wf[1][ks], vf, acc[1][n]);
      }
    }
    __builtin_amdgcn_s_setprio(0);

    bar_all();   // PV reads done by all; my HB prefetch landed (vmcnt 0)
    if (jt + 1 < NT){
      STAGE_VT(j0 + TJ);
      bar_all(); // VT landed; HBT also guaranteed for next QK
    }
  }
  #undef STAGE_HB
  #undef STAGE_VT

  // ---- finish: q-reduce s (row p layout), transpose via SST, normalize, store
  s_run[0] += __shfl_xor(s_run[0], 16, 64);
  s_run[0] += __shfl_xor(s_run[0], 32, 64);
  s_run[1] += __shfl_xor(s_run[1], 16, 64);
  s_run[1] += __shfl_xor(s_run[1], 32, 64);
  if (q == 0){
    SST[wid][p]      = s_run[0];
    SST[wid][16 + p] = s_run[1];
  }
  __syncthreads();
  float invS[2][4];
  #pragma unroll
  for (int g = 0; g < 2; ++g)
    #pragma unroll
    for (int r = 0; r < 4; ++r){
      int idx = g*16 + q*4 + r;
      invS[g][r] = 1.0f / (SST[wr*2][idx] + SST[wr*2 + 1][idx]);
    }

  #pragma unroll
  for (int g = 0; g < 2; ++g)
    #pragma unroll
    for (int n = 0; n < 8; ++n)
      #pragma unroll
      for (int r = 0; r < 4; ++r){
        int row = i0 + wr*32 + g*16 + q*4 + r;
        outp[(size_t)row * D_ + wc*128 + n*16 + p] = acc[g][n][r] * invS[g][r];
      }
}

extern "C" void kernel_launch(void* const* d_in, const int* in_sizes, int n_in,
                              void* d_out, int out_size, void* d_ws, size_t ws_size,
                              hipStream_t stream) {
  const float* a      = (const float*)d_in[0];
  const float* b      = (const float*)d_in[1];
  const int*   mask_a = (const int*)d_in[2];
  const int*   mask_b = (const int*)d_in[3];
  const float* a_v    = (const float*)d_in[4];
  const float* a_g    = (const float*)d_in[5];
  const float* a_bias = (const float*)d_in[6];
  const float* b_v    = (const float*)d_in[7];
  const float* b_g    = (const float*)d_in[8];
  const float* b_bias = (const float*)d_in[9];
  const float* tau    = (const float*)d_in[10];

  float* out = (float*)d_out;

  char* ws = (char*)d_ws;
  const size_t SZ_W  = (size_t)H_ * D_ * 2;        // 128 KB
  const size_t SZ_H  = (size_t)B_ * L_ * H_ * 2;   // 8 MB
  unsigned short* wa = (unsigned short*)(ws);
  unsigned short* wb = (unsigned short*)(ws + SZ_W);
  unsigned short* ha = (unsigned short*)(ws + 2*SZ_W);
  unsigned short* hb = (unsigned short*)(ws + 2*SZ_W + SZ_H);
  unsigned short* aT = (unsigned short*)(ws + 2*SZ_W + 2*SZ_H);
  unsigned short* bT = (unsigned short*)(ws + 2*SZ_W + 3*SZ_H);
  float* rn_a = (float*)(ws + 2*SZ_W + 4*SZ_H);
  float* rn_b = rn_a + (size_t)B_ * L_;
  float* maxn = rn_b + (size_t)B_ * L_;            // 16 floats
  size_t need = 2*SZ_W + 4*SZ_H + 2*(size_t)B_*L_*4 + 64;
  if (ws_size < need) return;

  // 1. normalized weights (both, one launch) + maxn init
  wnorm_kernel<<<dim3(H_, 2), 256, 0, stream>>>(a_v, a_g, b_v, b_g, wa, wb, maxn);

  // 2. h = bf16(scale*relu(x@w^T+bias)) + transposed copies + row norms
  {
    dim3 g((B_*L_)/64, 2);
    hgemm_kernel<<<g, 256, 0, stream>>>(a, b, wa, wb, a_bias, b_bias, tau,
                                        ha, hb, aT, bT, rn_a, rn_b, maxn);
  }

  // 3. fused flash alignment, both directions (512 blocks = 2/CU, XCD-affine)
  {
    flash_kernel<<<dim3((L_/BM) * B_ * 2), 256, 0, stream>>>(
        ha, hb, aT, bT, mask_a, mask_b, rn_a, rn_b, maxn, out);
  }
}